// Round 1
// baseline (808.513 us; speedup 1.0000x reference)
//
#include <hip/hip_runtime.h>
#include <hip/hip_bf16.h>
#include <math.h>

// DecoderLayer: B=4, S=2048, D=1024, H=16, DK=64, DFF=1024, fp32 in/out.
// Strategy: bf16 MFMA (16x16x32) for all GEMMs + flash attention; fp32
// residual path kept exact. Workspace layout (bytes):
//   [0,12MB)  : 6 bf16 weight copies (2MB each)
//   [12,28MB) : x2a bf16 (norm1 out; reused as attention output)
//   [28,44MB) : Q bf16  (reused as norm2 out)
//   [44,60MB) : K bf16  (reused as FF hidden)
//   [60,76MB) : V bf16

#define B_ 4
#define S_ 2048
#define D_ 1024
#define H_ 16
#define DFF_ 1024

typedef __attribute__((ext_vector_type(8))) short short8;
typedef __attribute__((ext_vector_type(8))) unsigned short ushort8;
typedef __attribute__((ext_vector_type(4))) float f32x4;

__device__ __forceinline__ unsigned short f2bf(float f) {
  __hip_bfloat16 h = __float2bfloat16(f);
  return *reinterpret_cast<unsigned short*>(&h);
}

// ---------------- fp32 -> bf16 cast (vectorized) ----------------
__global__ void cast_k(const float* __restrict__ src,
                       unsigned short* __restrict__ dst, int n4) {
  int i = blockIdx.x * blockDim.x + threadIdx.x;
  if (i >= n4) return;
  float4 v = reinterpret_cast<const float4*>(src)[i];
  ushort4 o;
  o.x = f2bf(v.x); o.y = f2bf(v.y); o.z = f2bf(v.z); o.w = f2bf(v.w);
  reinterpret_cast<ushort4*>(dst)[i] = o;
}

// ---------------- LayerNorm (torch: unbiased std, /(std+eps)) ----------------
__global__ __launch_bounds__(256) void ln_k(const float* __restrict__ x,
                                            const float* __restrict__ alpha,
                                            const float* __restrict__ bias,
                                            unsigned short* __restrict__ out) {
  int row = blockIdx.x, t = threadIdx.x;
  float4 v = reinterpret_cast<const float4*>(x + (size_t)row * D_)[t];
  float s = v.x + v.y + v.z + v.w;
  float q = v.x*v.x + v.y*v.y + v.z*v.z + v.w*v.w;
#pragma unroll
  for (int off = 32; off > 0; off >>= 1) {
    s += __shfl_down(s, off);
    q += __shfl_down(q, off);
  }
  __shared__ float ss[4], sq[4], stat[2];
  if ((t & 63) == 0) { ss[t >> 6] = s; sq[t >> 6] = q; }
  __syncthreads();
  if (t == 0) {
    float S = ss[0] + ss[1] + ss[2] + ss[3];
    float Q = sq[0] + sq[1] + sq[2] + sq[3];
    float mean = S * (1.0f / D_);
    float var = fmaxf((Q - D_ * mean * mean) * (1.0f / (D_ - 1)), 0.0f);
    stat[0] = mean;
    stat[1] = 1.0f / (sqrtf(var) + 1e-6f);
  }
  __syncthreads();
  float mean = stat[0], inv = stat[1];
  float4 a = reinterpret_cast<const float4*>(alpha)[t];
  float4 b = reinterpret_cast<const float4*>(bias)[t];
  ushort4 o;
  o.x = f2bf((v.x - mean) * inv * a.x + b.x);
  o.y = f2bf((v.y - mean) * inv * a.y + b.y);
  o.z = f2bf((v.z - mean) * inv * a.z + b.z);
  o.w = f2bf((v.w - mean) * inv * a.w + b.w);
  reinterpret_cast<ushort4*>(out + (size_t)row * D_)[t] = o;
}

// ---------------- bf16 MFMA GEMM: C[M,N] = A[M,K] @ W[K,N] (+bias,res,gelu) ----
// 128x128 tile, BK=32, 4 waves in 2x2, each wave 64x64 (4x4 of 16x16x32 MFMA).
// flags: bit0 = bf16 out, bit1 = gelu. res != null -> add fp32 residual.
__global__ __launch_bounds__(256) void gemm_k(
    const unsigned short* __restrict__ A, const unsigned short* __restrict__ W,
    const float* __restrict__ bias, const float* __restrict__ res,
    void* __restrict__ outp, int M, int N, int K, int flags) {
  __shared__ unsigned short As[128 * 40];  // [m][k], +8 pad
  __shared__ unsigned short Bs[128 * 40];  // [n][k] (transposed), +8 pad
  const int t = threadIdx.x;
  const int m0 = blockIdx.y * 128, n0 = blockIdx.x * 128;
  const int wv = t >> 6, lane = t & 63, quad = lane >> 4, l16 = lane & 15;
  const int wm = wv >> 1, wn = wv & 1;

  f32x4 acc[4][4] = {};

  const int arow = t >> 1, akseg = (t & 1) * 16;
  const int bk = t & 31, bnseg = (t >> 5) * 16;
  const unsigned short* Ap = A + (size_t)(m0 + arow) * K + akseg;
  const unsigned short* Wp = W + (size_t)bk * N + n0 + bnseg;

  for (int k0 = 0; k0 < K; k0 += 32) {
    ushort8 a0 = *reinterpret_cast<const ushort8*>(Ap);
    ushort8 a1 = *reinterpret_cast<const ushort8*>(Ap + 8);
    ushort8 b0 = *reinterpret_cast<const ushort8*>(Wp);
    ushort8 b1 = *reinterpret_cast<const ushort8*>(Wp + 8);
    *reinterpret_cast<ushort8*>(&As[arow * 40 + akseg]) = a0;
    *reinterpret_cast<ushort8*>(&As[arow * 40 + akseg + 8]) = a1;
#pragma unroll
    for (int j = 0; j < 8; ++j) Bs[(bnseg + j) * 40 + bk] = b0[j];
#pragma unroll
    for (int j = 0; j < 8; ++j) Bs[(bnseg + 8 + j) * 40 + bk] = b1[j];
    __syncthreads();

    short8 af[4], bf[4];
#pragma unroll
    for (int mt = 0; mt < 4; ++mt)
      af[mt] = *reinterpret_cast<const short8*>(
          &As[(wm * 64 + mt * 16 + l16) * 40 + quad * 8]);
#pragma unroll
    for (int nt = 0; nt < 4; ++nt)
      bf[nt] = *reinterpret_cast<const short8*>(
          &Bs[(wn * 64 + nt * 16 + l16) * 40 + quad * 8]);
#pragma unroll
    for (int mt = 0; mt < 4; ++mt)
#pragma unroll
      for (int nt = 0; nt < 4; ++nt)
        acc[mt][nt] = __builtin_amdgcn_mfma_f32_16x16x32_bf16(
            af[mt], bf[nt], acc[mt][nt], 0, 0, 0);
    __syncthreads();
    Ap += 32;
    Wp += (size_t)32 * N;
  }

  const bool obf = flags & 1, dog = flags & 2;
#pragma unroll
  for (int nt = 0; nt < 4; ++nt) {
    int col = n0 + wn * 64 + nt * 16 + l16;
    float bv = bias[col];
#pragma unroll
    for (int mt = 0; mt < 4; ++mt) {
#pragma unroll
      for (int r = 0; r < 4; ++r) {
        int row = m0 + wm * 64 + mt * 16 + quad * 4 + r;
        float v = acc[mt][nt][r] + bv;
        if (res) v += res[(size_t)row * N + col];
        if (dog)
          v = 0.5f * v *
              (1.0f + tanhf(0.7978845608028654f * (v + 0.044715f * v * v * v)));
        if (obf)
          ((unsigned short*)outp)[(size_t)row * N + col] = f2bf(v);
        else
          ((float*)outp)[(size_t)row * N + col] = v;
      }
    }
  }
}

// ---------------- causal flash attention ----------------
// grid (S/128, H, B); block 256 = 4 waves; wave w handles 32 queries.
// K-tiles of 32 keys staged to LDS (V transposed). P transits LDS (C->A layout).
__global__ __launch_bounds__(256) void attn_k(
    const unsigned short* __restrict__ Q, const unsigned short* __restrict__ Kg,
    const unsigned short* __restrict__ Vg, unsigned short* __restrict__ Og) {
  __shared__ unsigned short Ks[32 * 72];      // [k][d], pad 64->72
  __shared__ unsigned short Vt[64 * 40];      // [d][k], pad 32->40
  __shared__ unsigned short Ps[4 * 32 * 40];  // per-wave P, [q][k] pad 32->40
  const int t = threadIdx.x;
  const int b = blockIdx.z, h = blockIdx.y, q0 = blockIdx.x * 128;
  const int w = t >> 6, lane = t & 63, quad = lane >> 4, l16 = lane & 15;
  const int qw0 = q0 + w * 32;

  short8 qf[2][2];
#pragma unroll
  for (int mt = 0; mt < 2; ++mt)
#pragma unroll
    for (int dc = 0; dc < 2; ++dc)
      qf[mt][dc] = *reinterpret_cast<const short8*>(
          Q + (size_t)(b * S_ + qw0 + mt * 16 + l16) * D_ + h * 64 + dc * 32 +
          quad * 8);

  f32x4 O[2][4] = {};
  float m_r[2][4], l_r[2][4];
#pragma unroll
  for (int mt = 0; mt < 2; ++mt)
#pragma unroll
    for (int r = 0; r < 4; ++r) { m_r[mt][r] = -1e30f; l_r[mt][r] = 0.0f; }

  const int ktiles = (q0 >> 5) + 4;
  const int sk = t >> 3, sd0 = (t & 7) * 8;   // K staging: coalesced rows
  const int vk = t & 31, vd0 = (t >> 5) * 8;  // V staging: conflict-free LDS

  for (int kt = 0; kt < ktiles; ++kt) {
    {
      ushort8 kv = *reinterpret_cast<const ushort8*>(
          Kg + (size_t)(b * S_ + kt * 32 + sk) * D_ + h * 64 + sd0);
      *reinterpret_cast<ushort8*>(&Ks[sk * 72 + sd0]) = kv;
      ushort8 vv = *reinterpret_cast<const ushort8*>(
          Vg + (size_t)(b * S_ + kt * 32 + vk) * D_ + h * 64 + vd0);
#pragma unroll
      for (int j = 0; j < 8; ++j) Vt[(vd0 + j) * 40 + vk] = vv[j];
    }
    __syncthreads();

    short8 kf[2][2];
#pragma unroll
    for (int nh = 0; nh < 2; ++nh)
#pragma unroll
      for (int dc = 0; dc < 2; ++dc)
        kf[nh][dc] = *reinterpret_cast<const short8*>(
            &Ks[(nh * 16 + l16) * 72 + dc * 32 + quad * 8]);

    f32x4 sc[2][2] = {};
#pragma unroll
    for (int mt = 0; mt < 2; ++mt)
#pragma unroll
      for (int nh = 0; nh < 2; ++nh) {
        sc[mt][nh] = __builtin_amdgcn_mfma_f32_16x16x32_bf16(
            qf[mt][0], kf[nh][0], sc[mt][nh], 0, 0, 0);
        sc[mt][nh] = __builtin_amdgcn_mfma_f32_16x16x32_bf16(
            qf[mt][1], kf[nh][1], sc[mt][nh], 0, 0, 0);
      }

#pragma unroll
    for (int mt = 0; mt < 2; ++mt)
#pragma unroll
      for (int r = 0; r < 4; ++r) {
        int row = qw0 + mt * 16 + quad * 4 + r;
        int c0 = kt * 32 + l16;
        float s0 = sc[mt][0][r] * 0.125f;
        if (c0 > row) s0 = -1e9f;
        float s1 = sc[mt][1][r] * 0.125f;
        if (c0 + 16 > row) s1 = -1e9f;
        float mx = fmaxf(s0, s1);
#pragma unroll
        for (int off = 1; off < 16; off <<= 1) mx = fmaxf(mx, __shfl_xor(mx, off));
        float mn = fmaxf(m_r[mt][r], mx);
        float p0 = __expf(s0 - mn), p1 = __expf(s1 - mn);
        float rs = p0 + p1;
#pragma unroll
        for (int off = 1; off < 16; off <<= 1) rs += __shfl_xor(rs, off);
        float al = __expf(m_r[mt][r] - mn);
        m_r[mt][r] = mn;
        l_r[mt][r] = l_r[mt][r] * al + rs;
        int prow = mt * 16 + quad * 4 + r;
        Ps[(w * 32 + prow) * 40 + l16] = f2bf(p0);
        Ps[(w * 32 + prow) * 40 + 16 + l16] = f2bf(p1);
#pragma unroll
        for (int nd = 0; nd < 4; ++nd) O[mt][nd][r] *= al;
      }
    __syncthreads();

    short8 pf[2], vf[4];
#pragma unroll
    for (int mt = 0; mt < 2; ++mt)
      pf[mt] = *reinterpret_cast<const short8*>(
          &Ps[(w * 32 + mt * 16 + l16) * 40 + quad * 8]);
#pragma unroll
    for (int nd = 0; nd < 4; ++nd)
      vf[nd] = *reinterpret_cast<const short8*>(
          &Vt[(nd * 16 + l16) * 40 + quad * 8]);
#pragma unroll
    for (int mt = 0; mt < 2; ++mt)
#pragma unroll
      for (int nd = 0; nd < 4; ++nd)
        O[mt][nd] = __builtin_amdgcn_mfma_f32_16x16x32_bf16(pf[mt], vf[nd],
                                                            O[mt][nd], 0, 0, 0);
    __syncthreads();
  }

#pragma unroll
  for (int mt = 0; mt < 2; ++mt)
#pragma unroll
    for (int nd = 0; nd < 4; ++nd)
#pragma unroll
      for (int r = 0; r < 4; ++r) {
        int row = qw0 + mt * 16 + quad * 4 + r;
        float val = O[mt][nd][r] / l_r[mt][r];
        Og[(size_t)(b * S_ + row) * D_ + h * 64 + nd * 16 + l16] = f2bf(val);
      }
}

extern "C" void kernel_launch(void* const* d_in, const int* in_sizes, int n_in,
                              void* d_out, int out_size, void* d_ws,
                              size_t ws_size, hipStream_t stream) {
  const float* x = (const float*)d_in[0];
  // d_in[1] = mask (causal tril; hardcoded in attn kernel)
  const float* Wq = (const float*)d_in[2];
  const float* bq = (const float*)d_in[3];
  const float* Wk = (const float*)d_in[4];
  const float* bk = (const float*)d_in[5];
  const float* Wv = (const float*)d_in[6];
  const float* bv = (const float*)d_in[7];
  const float* Wo = (const float*)d_in[8];
  const float* bo = (const float*)d_in[9];
  const float* W1 = (const float*)d_in[10];
  const float* b1 = (const float*)d_in[11];
  const float* W2 = (const float*)d_in[12];
  const float* b2 = (const float*)d_in[13];
  const float* alpha1 = (const float*)d_in[14];
  const float* bias1 = (const float*)d_in[15];
  const float* alpha2 = (const float*)d_in[16];
  const float* bias2 = (const float*)d_in[17];
  float* out = (float*)d_out;

  char* ws = (char*)d_ws;
  const size_t MB = 1024 * 1024;
  unsigned short* wqb = (unsigned short*)(ws + 0 * MB);
  unsigned short* wkb = (unsigned short*)(ws + 2 * MB);
  unsigned short* wvb = (unsigned short*)(ws + 4 * MB);
  unsigned short* wob = (unsigned short*)(ws + 6 * MB);
  unsigned short* w1b = (unsigned short*)(ws + 8 * MB);
  unsigned short* w2b = (unsigned short*)(ws + 10 * MB);
  unsigned short* x2a = (unsigned short*)(ws + 12 * MB);  // also attn output
  unsigned short* qb = (unsigned short*)(ws + 28 * MB);   // also norm2 output
  unsigned short* kb = (unsigned short*)(ws + 44 * MB);   // also FF hidden
  unsigned short* vb = (unsigned short*)(ws + 60 * MB);

  const int n4 = (1024 * 1024) / 4;
  cast_k<<<dim3(n4 / 256), dim3(256), 0, stream>>>(Wq, wqb, n4);
  cast_k<<<dim3(n4 / 256), dim3(256), 0, stream>>>(Wk, wkb, n4);
  cast_k<<<dim3(n4 / 256), dim3(256), 0, stream>>>(Wv, wvb, n4);
  cast_k<<<dim3(n4 / 256), dim3(256), 0, stream>>>(Wo, wob, n4);
  cast_k<<<dim3(n4 / 256), dim3(256), 0, stream>>>(W1, w1b, n4);
  cast_k<<<dim3(n4 / 256), dim3(256), 0, stream>>>(W2, w2b, n4);

  const int M = B_ * S_;  // 8192
  ln_k<<<dim3(M), dim3(256), 0, stream>>>(x, alpha1, bias1, x2a);

  dim3 gg(D_ / 128, M / 128);  // (8, 64)
  gemm_k<<<gg, dim3(256), 0, stream>>>(x2a, wqb, bq, nullptr, qb, M, D_, D_, 1);
  gemm_k<<<gg, dim3(256), 0, stream>>>(x2a, wkb, bk, nullptr, kb, M, D_, D_, 1);
  gemm_k<<<gg, dim3(256), 0, stream>>>(x2a, wvb, bv, nullptr, vb, M, D_, D_, 1);

  attn_k<<<dim3(S_ / 128, H_, B_), dim3(256), 0, stream>>>(qb, kb, vb, x2a);

  // x = x + attn @ Wo + bo  (fp32 into d_out)
  gemm_k<<<gg, dim3(256), 0, stream>>>(x2a, wob, bo, x, out, M, D_, D_, 0);

  ln_k<<<dim3(M), dim3(256), 0, stream>>>(out, alpha2, bias2, qb);

  // h = gelu(x2 @ W1 + b1)  (bf16)
  gemm_k<<<gg, dim3(256), 0, stream>>>(qb, w1b, b1, nullptr, kb, M, DFF_, D_, 3);

  // out = out + h @ W2 + b2  (fp32, in-place on d_out)
  gemm_k<<<gg, dim3(256), 0, stream>>>(kb, w2b, b2, out, out, M, D_, DFF_, 0);
}

// Round 2
// 545.079 us; speedup vs baseline: 1.4833x; 1.4833x over previous
//
#include <hip/hip_runtime.h>
#include <hip/hip_bf16.h>
#include <math.h>

// DecoderLayer: B=4, S=2048, D=1024, H=16, DK=64, DFF=1024, fp32 in/out.
// bf16 MFMA everywhere; fp32 residual path. R1: m97-style GEMM
// (global_load_lds width=16 + XOR-swizzled LDS, pre-transposed weights),
// attention with 64-key tiles, 2 barriers/tile, heavy-first block order,
// V pre-transposed by the V-GEMM epilogue.
// Workspace: [0,12MB) 6x bf16 W^T; [12,28) x2a/attn-out; [28,44) Q/norm2;
//            [44,60) K/FF-hidden; [60,76) VT[b][h][d][s].

#define B_ 4
#define S_ 2048
#define D_ 1024
#define H_ 16
#define DFF_ 1024

typedef __attribute__((ext_vector_type(8))) short short8;
typedef __attribute__((ext_vector_type(8))) unsigned short ushort8;
typedef __attribute__((ext_vector_type(4))) float f32x4;

__device__ __forceinline__ unsigned short f2bf(float f) {
  __hip_bfloat16 h = __float2bfloat16(f);
  return *reinterpret_cast<unsigned short*>(&h);
}

__device__ __forceinline__ void gload16(const void* g, void* l) {
  __builtin_amdgcn_global_load_lds(
      (const __attribute__((address_space(1))) void*)g,
      (__attribute__((address_space(3))) void*)l, 16, 0, 0);
}

// ---------- transpose + cast: src[K][N] fp32 -> dst[N][K] bf16 ----------
__global__ __launch_bounds__(256) void tcast_k(const float* __restrict__ src,
                                               unsigned short* __restrict__ dst,
                                               int K, int N) {
  __shared__ float tile[64][65];
  const int k0 = blockIdx.y * 64, n0 = blockIdx.x * 64;
  const int t = threadIdx.x;
  const int r = t >> 2, c0 = (t & 3) * 16;
  const float4* sp =
      reinterpret_cast<const float4*>(src + (size_t)(k0 + r) * N + n0 + c0);
#pragma unroll
  for (int j = 0; j < 4; ++j) {
    float4 v = sp[j];
    tile[r][c0 + 4 * j] = v.x;
    tile[r][c0 + 4 * j + 1] = v.y;
    tile[r][c0 + 4 * j + 2] = v.z;
    tile[r][c0 + 4 * j + 3] = v.w;
  }
  __syncthreads();
  ushort8 o0, o1;
#pragma unroll
  for (int j = 0; j < 8; ++j) o0[j] = f2bf(tile[c0 + j][r]);
#pragma unroll
  for (int j = 0; j < 8; ++j) o1[j] = f2bf(tile[c0 + 8 + j][r]);
  unsigned short* dp = dst + (size_t)(n0 + r) * K + k0 + c0;
  *reinterpret_cast<ushort8*>(dp) = o0;
  *reinterpret_cast<ushort8*>(dp + 8) = o1;
}

// ---------- LayerNorm (torch: unbiased std, /(std+eps)) ----------
__global__ __launch_bounds__(256) void ln_k(const float* __restrict__ x,
                                            const float* __restrict__ alpha,
                                            const float* __restrict__ bias,
                                            unsigned short* __restrict__ out) {
  int row = blockIdx.x, t = threadIdx.x;
  float4 v = reinterpret_cast<const float4*>(x + (size_t)row * D_)[t];
  float s = v.x + v.y + v.z + v.w;
  float q = v.x * v.x + v.y * v.y + v.z * v.z + v.w * v.w;
#pragma unroll
  for (int off = 32; off > 0; off >>= 1) {
    s += __shfl_down(s, off);
    q += __shfl_down(q, off);
  }
  __shared__ float ss[4], sq[4], stat[2];
  if ((t & 63) == 0) { ss[t >> 6] = s; sq[t >> 6] = q; }
  __syncthreads();
  if (t == 0) {
    float S = ss[0] + ss[1] + ss[2] + ss[3];
    float Q = sq[0] + sq[1] + sq[2] + sq[3];
    float mean = S * (1.0f / D_);
    float var = fmaxf((Q - D_ * mean * mean) * (1.0f / (D_ - 1)), 0.0f);
    stat[0] = mean;
    stat[1] = 1.0f / (sqrtf(var) + 1e-6f);
  }
  __syncthreads();
  float mean = stat[0], inv = stat[1];
  float4 a = reinterpret_cast<const float4*>(alpha)[t];
  float4 b = reinterpret_cast<const float4*>(bias)[t];
  ushort4 o;
  o.x = f2bf((v.x - mean) * inv * a.x + b.x);
  o.y = f2bf((v.y - mean) * inv * a.y + b.y);
  o.z = f2bf((v.z - mean) * inv * a.z + b.z);
  o.w = f2bf((v.w - mean) * inv * a.w + b.w);
  reinterpret_cast<ushort4*>(out + (size_t)row * D_)[t] = o;
}

// ---------- GEMM: C[M,N] = A[M,K] @ Wt[N,K]^T, m97-style staging ----------
// flags: 1 = bf16 natural out, 2 = gelu, 4 = bf16 VT out [b][h][dk][S]
__global__ __launch_bounds__(256) void gemm_k(
    const unsigned short* __restrict__ A, const unsigned short* __restrict__ Wt,
    const float* __restrict__ bias, const float* __restrict__ res,
    void* __restrict__ outp, int M, int N, int K, int flags) {
  __shared__ unsigned short As[128 * 32];  // [row][k], kseg XOR-swizzled
  __shared__ unsigned short Bs[128 * 32];
  const int t = threadIdx.x;
  const int m0 = blockIdx.y * 128, n0 = blockIdx.x * 128;
  const int wv = t >> 6, lane = t & 63, quad = lane >> 4, l16 = lane & 15;
  const int wm = wv >> 1, wn = wv & 1;
  f32x4 acc[4][4] = {};

  // staging: wave wv fills rows [32*wv, 32*wv+32) as two 1KB lane-contiguous
  // chunks; element (row, kseg q) lives at physical slot q ^ ((row>>1)&3).
  const int row0 = wv * 32 + (lane >> 2);
  const int row1 = row0 + 16;
  const int slot = lane & 3;
  const int kof0 = ((slot ^ ((row0 >> 1) & 3)) << 3);
  const int kof1 = ((slot ^ ((row1 >> 1) & 3)) << 3);
  const unsigned short* Ag0 = A + (size_t)(m0 + row0) * K + kof0;
  const unsigned short* Ag1 = A + (size_t)(m0 + row1) * K + kof1;
  const unsigned short* Bg0 = Wt + (size_t)(n0 + row0) * K + kof0;
  const unsigned short* Bg1 = Wt + (size_t)(n0 + row1) * K + kof1;
  unsigned short* la0 = &As[(wv * 32) * 32];
  unsigned short* la1 = &As[(wv * 32 + 16) * 32];
  unsigned short* lb0 = &Bs[(wv * 32) * 32];
  unsigned short* lb1 = &Bs[(wv * 32 + 16) * 32];

  for (int k0 = 0; k0 < K; k0 += 32) {
    gload16(Ag0, la0);
    gload16(Ag1, la1);
    gload16(Bg0, lb0);
    gload16(Bg1, lb1);
    __syncthreads();
    short8 af[4], bf[4];
#pragma unroll
    for (int mt = 0; mt < 4; ++mt) {
      int r = wm * 64 + mt * 16 + l16;
      af[mt] = *reinterpret_cast<const short8*>(
          &As[r * 32 + ((quad ^ ((r >> 1) & 3)) << 3)]);
    }
#pragma unroll
    for (int nt = 0; nt < 4; ++nt) {
      int r = wn * 64 + nt * 16 + l16;
      bf[nt] = *reinterpret_cast<const short8*>(
          &Bs[r * 32 + ((quad ^ ((r >> 1) & 3)) << 3)]);
    }
#pragma unroll
    for (int mt = 0; mt < 4; ++mt)
#pragma unroll
      for (int nt = 0; nt < 4; ++nt)
        acc[mt][nt] = __builtin_amdgcn_mfma_f32_16x16x32_bf16(
            af[mt], bf[nt], acc[mt][nt], 0, 0, 0);
    __syncthreads();
    Ag0 += 32; Ag1 += 32; Bg0 += 32; Bg1 += 32;
  }

  if (flags & 4) {  // V-GEMM: write VT[b][h][dk][S] bf16
    unsigned short* VT = (unsigned short*)outp;
#pragma unroll
    for (int nt = 0; nt < 4; ++nt) {
      int col = n0 + wn * 64 + nt * 16 + l16;
      float bv = bias[col];
      int h = col >> 6, dk = col & 63;
#pragma unroll
      for (int mt = 0; mt < 4; ++mt) {
        int m = m0 + wm * 64 + mt * 16 + quad * 4;
        int b = m >> 11, sidx = m & 2047;
        ushort4 o;
        o.x = f2bf(acc[mt][nt][0] + bv);
        o.y = f2bf(acc[mt][nt][1] + bv);
        o.z = f2bf(acc[mt][nt][2] + bv);
        o.w = f2bf(acc[mt][nt][3] + bv);
        *reinterpret_cast<ushort4*>(
            &VT[(((size_t)(b * 16 + h) * 64 + dk) * 2048 + sidx)]) = o;
      }
    }
    return;
  }
  const bool obf = flags & 1, dog = flags & 2;
#pragma unroll
  for (int nt = 0; nt < 4; ++nt) {
    int col = n0 + wn * 64 + nt * 16 + l16;
    float bv = bias[col];
#pragma unroll
    for (int mt = 0; mt < 4; ++mt) {
#pragma unroll
      for (int r = 0; r < 4; ++r) {
        int row = m0 + wm * 64 + mt * 16 + quad * 4 + r;
        float v = acc[mt][nt][r] + bv;
        if (res) v += res[(size_t)row * N + col];
        if (dog) {
          float e = __expf(1.5957691216057308f * (v + 0.044715f * v * v * v));
          float th = 1.0f - 2.0f / (1.0f + e);
          v = 0.5f * v * (1.0f + th);
        }
        if (obf)
          ((unsigned short*)outp)[(size_t)row * N + col] = f2bf(v);
        else
          ((float*)outp)[(size_t)row * N + col] = v;
      }
    }
  }
}

// ---------- causal flash attention, 64-key tiles ----------
// 1024 blocks (heavy-first), 4 waves; wave w: 32 queries. V from VT[b][h][d][s].
__global__ __launch_bounds__(256) void attn_k(
    const unsigned short* __restrict__ Q, const unsigned short* __restrict__ Kg,
    const unsigned short* __restrict__ VT, unsigned short* __restrict__ Og) {
  __shared__ unsigned short Ks[64 * 72];      // [k][d] +8 pad
  __shared__ unsigned short Vs[64 * 72];      // [d][k] +8 pad
  __shared__ unsigned short Ps[4 * 32 * 72];  // per-wave P [q][k] +8 pad
  const int t = threadIdx.x;
  const int bid = blockIdx.x;
  const int bx = 15 - (bid >> 6);  // heavy blocks first
  const int bh = bid & 63;
  const int b = bh >> 4, h = bh & 15;
  const int q0 = bx * 128;
  const int w = t >> 6, lane = t & 63, quad = lane >> 4, l16 = lane & 15;
  const int qw0 = q0 + w * 32;

  short8 qf[2][2];
#pragma unroll
  for (int mt = 0; mt < 2; ++mt)
#pragma unroll
    for (int dc = 0; dc < 2; ++dc)
      qf[mt][dc] = *reinterpret_cast<const short8*>(
          Q + (size_t)(b * S_ + qw0 + mt * 16 + l16) * D_ + h * 64 + dc * 32 +
          quad * 8);

  f32x4 O[2][4] = {};
  float m_r[2][4], l_r[2][4];
#pragma unroll
  for (int mt = 0; mt < 2; ++mt)
#pragma unroll
    for (int r = 0; r < 4; ++r) { m_r[mt][r] = -1e30f; l_r[mt][r] = 0.0f; }

  const int ktiles = 2 * bx + 2;
  const int srow = t >> 2, sseg = (t & 3) * 16;
  const unsigned short* Kp =
      Kg + (size_t)(b * S_ + srow) * D_ + h * 64 + sseg;  // += 64*D_ per tile
  const unsigned short* Vp =
      VT + ((size_t)(b * 16 + h) * 64 + srow) * 2048 + sseg;  // += 64 per tile

  for (int kt = 0; kt < ktiles; ++kt) {
    {
      ushort8 ka = *reinterpret_cast<const ushort8*>(Kp);
      ushort8 kb2 = *reinterpret_cast<const ushort8*>(Kp + 8);
      ushort8 va = *reinterpret_cast<const ushort8*>(Vp);
      ushort8 vb2 = *reinterpret_cast<const ushort8*>(Vp + 8);
      *reinterpret_cast<ushort8*>(&Ks[srow * 72 + sseg]) = ka;
      *reinterpret_cast<ushort8*>(&Ks[srow * 72 + sseg + 8]) = kb2;
      *reinterpret_cast<ushort8*>(&Vs[srow * 72 + sseg]) = va;
      *reinterpret_cast<ushort8*>(&Vs[srow * 72 + sseg + 8]) = vb2;
    }
    __syncthreads();

    f32x4 sc[2][4] = {};
#pragma unroll
    for (int nh = 0; nh < 4; ++nh) {
      short8 kf0 = *reinterpret_cast<const short8*>(
          &Ks[(nh * 16 + l16) * 72 + quad * 8]);
      short8 kf1 = *reinterpret_cast<const short8*>(
          &Ks[(nh * 16 + l16) * 72 + 32 + quad * 8]);
#pragma unroll
      for (int mt = 0; mt < 2; ++mt) {
        sc[mt][nh] = __builtin_amdgcn_mfma_f32_16x16x32_bf16(
            qf[mt][0], kf0, sc[mt][nh], 0, 0, 0);
        sc[mt][nh] = __builtin_amdgcn_mfma_f32_16x16x32_bf16(
            qf[mt][1], kf1, sc[mt][nh], 0, 0, 0);
      }
    }

    const bool full = (kt * 64 + 63) <= qw0;
#pragma unroll
    for (int mt = 0; mt < 2; ++mt)
#pragma unroll
      for (int r = 0; r < 4; ++r) {
        int row = qw0 + mt * 16 + quad * 4 + r;
        float s[4];
#pragma unroll
        for (int nh = 0; nh < 4; ++nh) {
          s[nh] = sc[mt][nh][r] * 0.125f;
          if (!full && (kt * 64 + nh * 16 + l16) > row) s[nh] = -1e9f;
        }
        float mx = fmaxf(fmaxf(s[0], s[1]), fmaxf(s[2], s[3]));
#pragma unroll
        for (int off = 1; off < 16; off <<= 1)
          mx = fmaxf(mx, __shfl_xor(mx, off));
        float mn = fmaxf(m_r[mt][r], mx);
        float p[4], rs = 0.0f;
#pragma unroll
        for (int nh = 0; nh < 4; ++nh) { p[nh] = __expf(s[nh] - mn); rs += p[nh]; }
#pragma unroll
        for (int off = 1; off < 16; off <<= 1) rs += __shfl_xor(rs, off);
        float al = __expf(m_r[mt][r] - mn);
        m_r[mt][r] = mn;
        l_r[mt][r] = l_r[mt][r] * al + rs;
        int prow = w * 32 + mt * 16 + quad * 4 + r;
#pragma unroll
        for (int nh = 0; nh < 4; ++nh)
          Ps[prow * 72 + nh * 16 + l16] = f2bf(p[nh]);
#pragma unroll
        for (int nd = 0; nd < 4; ++nd) O[mt][nd][r] *= al;
      }

    // Ps is per-wave: no __syncthreads needed, just pin store->load order.
    __builtin_amdgcn_sched_barrier(0);

    short8 pf[2][2], vf[4][2];
#pragma unroll
    for (int mt = 0; mt < 2; ++mt)
#pragma unroll
      for (int kc = 0; kc < 2; ++kc)
        pf[mt][kc] = *reinterpret_cast<const short8*>(
            &Ps[(w * 32 + mt * 16 + l16) * 72 + kc * 32 + quad * 8]);
#pragma unroll
    for (int nd = 0; nd < 4; ++nd)
#pragma unroll
      for (int kc = 0; kc < 2; ++kc)
        vf[nd][kc] = *reinterpret_cast<const short8*>(
            &Vs[(nd * 16 + l16) * 72 + kc * 32 + quad * 8]);
#pragma unroll
    for (int mt = 0; mt < 2; ++mt)
#pragma unroll
      for (int nd = 0; nd < 4; ++nd) {
        O[mt][nd] = __builtin_amdgcn_mfma_f32_16x16x32_bf16(
            pf[mt][0], vf[nd][0], O[mt][nd], 0, 0, 0);
        O[mt][nd] = __builtin_amdgcn_mfma_f32_16x16x32_bf16(
            pf[mt][1], vf[nd][1], O[mt][nd], 0, 0, 0);
      }
    __syncthreads();
    Kp += (size_t)64 * D_;
    Vp += 64;
  }

#pragma unroll
  for (int mt = 0; mt < 2; ++mt)
#pragma unroll
    for (int nd = 0; nd < 4; ++nd)
#pragma unroll
      for (int r = 0; r < 4; ++r) {
        int row = qw0 + mt * 16 + quad * 4 + r;
        Og[(size_t)(b * S_ + row) * D_ + h * 64 + nd * 16 + l16] =
            f2bf(O[mt][nd][r] / l_r[mt][r]);
      }
}

extern "C" void kernel_launch(void* const* d_in, const int* in_sizes, int n_in,
                              void* d_out, int out_size, void* d_ws,
                              size_t ws_size, hipStream_t stream) {
  const float* x = (const float*)d_in[0];
  const float* Wq = (const float*)d_in[2];
  const float* bq = (const float*)d_in[3];
  const float* Wk = (const float*)d_in[4];
  const float* bk = (const float*)d_in[5];
  const float* Wv = (const float*)d_in[6];
  const float* bv = (const float*)d_in[7];
  const float* Wo = (const float*)d_in[8];
  const float* bo = (const float*)d_in[9];
  const float* W1 = (const float*)d_in[10];
  const float* b1 = (const float*)d_in[11];
  const float* W2 = (const float*)d_in[12];
  const float* b2 = (const float*)d_in[13];
  const float* alpha1 = (const float*)d_in[14];
  const float* bias1 = (const float*)d_in[15];
  const float* alpha2 = (const float*)d_in[16];
  const float* bias2 = (const float*)d_in[17];
  float* out = (float*)d_out;

  char* ws = (char*)d_ws;
  const size_t MB = 1024 * 1024;
  unsigned short* wqT = (unsigned short*)(ws + 0 * MB);
  unsigned short* wkT = (unsigned short*)(ws + 2 * MB);
  unsigned short* wvT = (unsigned short*)(ws + 4 * MB);
  unsigned short* woT = (unsigned short*)(ws + 6 * MB);
  unsigned short* w1T = (unsigned short*)(ws + 8 * MB);
  unsigned short* w2T = (unsigned short*)(ws + 10 * MB);
  unsigned short* x2a = (unsigned short*)(ws + 12 * MB);  // norm1 / attn out
  unsigned short* qb = (unsigned short*)(ws + 28 * MB);   // Q / norm2
  unsigned short* kb = (unsigned short*)(ws + 44 * MB);   // K / FF hidden
  unsigned short* vtb = (unsigned short*)(ws + 60 * MB);  // VT[b][h][d][s]

  dim3 tg(16, 16);
  tcast_k<<<tg, dim3(256), 0, stream>>>(Wq, wqT, D_, D_);
  tcast_k<<<tg, dim3(256), 0, stream>>>(Wk, wkT, D_, D_);
  tcast_k<<<tg, dim3(256), 0, stream>>>(Wv, wvT, D_, D_);
  tcast_k<<<tg, dim3(256), 0, stream>>>(Wo, woT, D_, D_);
  tcast_k<<<tg, dim3(256), 0, stream>>>(W1, w1T, DFF_, D_);
  tcast_k<<<tg, dim3(256), 0, stream>>>(W2, w2T, D_, DFF_);

  const int M = B_ * S_;  // 8192
  ln_k<<<dim3(M), dim3(256), 0, stream>>>(x, alpha1, bias1, x2a);

  dim3 gg(D_ / 128, M / 128);  // (8, 64)
  gemm_k<<<gg, dim3(256), 0, stream>>>(x2a, wqT, bq, nullptr, qb, M, D_, D_, 1);
  gemm_k<<<gg, dim3(256), 0, stream>>>(x2a, wkT, bk, nullptr, kb, M, D_, D_, 1);
  gemm_k<<<gg, dim3(256), 0, stream>>>(x2a, wvT, bv, nullptr, vtb, M, D_, D_, 4);

  attn_k<<<dim3(1024), dim3(256), 0, stream>>>(qb, kb, vtb, x2a);

  gemm_k<<<gg, dim3(256), 0, stream>>>(x2a, woT, bo, x, out, M, D_, D_, 0);

  ln_k<<<dim3(M), dim3(256), 0, stream>>>(out, alpha2, bias2, qb);

  gemm_k<<<gg, dim3(256), 0, stream>>>(qb, w1T, b1, nullptr, kb, M, DFF_, D_, 3);

  gemm_k<<<gg, dim3(256), 0, stream>>>(kb, w2T, b2, out, out, M, D_, DFF_, 0);
}

// Round 3
// 494.757 us; speedup vs baseline: 1.6342x; 1.1017x over previous
//
#include <hip/hip_runtime.h>
#include <hip/hip_bf16.h>
#include <math.h>

// DecoderLayer: B=4, S=2048, D=1024, H=16, DK=64, DFF=1024, fp32 in/out.
// R2: uniform-work paired attention (q-tiles p & 15-p per block, 34 key-tiles
// each), K/V staged via global_load_lds w/ XOR swizzle; fused QKV GEMM
// (N=3072); BK=64 GEMM loop (32 MFMA per barrier-pair).
// Workspace: [0,6MB) wq/wk/wv^T (contiguous = fused [3072][1024]);
// [6,12) wo/w1/w2^T; [12,28) x2a; [28,44) Q/norm2; [44,60) K/FFh; [60,76) VT.

#define B_ 4
#define S_ 2048
#define D_ 1024
#define H_ 16
#define DFF_ 1024

typedef __attribute__((ext_vector_type(8))) short short8;
typedef __attribute__((ext_vector_type(8))) unsigned short ushort8;
typedef __attribute__((ext_vector_type(4))) float f32x4;

__device__ __forceinline__ unsigned short f2bf(float f) {
  __hip_bfloat16 h = __float2bfloat16(f);
  return *reinterpret_cast<unsigned short*>(&h);
}

__device__ __forceinline__ void gload16(const void* g, void* l) {
  __builtin_amdgcn_global_load_lds(
      (const __attribute__((address_space(1))) void*)g,
      (__attribute__((address_space(3))) void*)l, 16, 0, 0);
}

// ---------- transpose + cast: src[K][N] fp32 -> dst[N][K] bf16 ----------
__global__ __launch_bounds__(256) void tcast_k(const float* __restrict__ src,
                                               unsigned short* __restrict__ dst,
                                               int K, int N) {
  __shared__ float tile[64][65];
  const int k0 = blockIdx.y * 64, n0 = blockIdx.x * 64;
  const int t = threadIdx.x;
  const int r = t >> 2, c0 = (t & 3) * 16;
  const float4* sp =
      reinterpret_cast<const float4*>(src + (size_t)(k0 + r) * N + n0 + c0);
#pragma unroll
  for (int j = 0; j < 4; ++j) {
    float4 v = sp[j];
    tile[r][c0 + 4 * j] = v.x;
    tile[r][c0 + 4 * j + 1] = v.y;
    tile[r][c0 + 4 * j + 2] = v.z;
    tile[r][c0 + 4 * j + 3] = v.w;
  }
  __syncthreads();
  ushort8 o0, o1;
#pragma unroll
  for (int j = 0; j < 8; ++j) o0[j] = f2bf(tile[c0 + j][r]);
#pragma unroll
  for (int j = 0; j < 8; ++j) o1[j] = f2bf(tile[c0 + 8 + j][r]);
  unsigned short* dp = dst + (size_t)(n0 + r) * K + k0 + c0;
  *reinterpret_cast<ushort8*>(dp) = o0;
  *reinterpret_cast<ushort8*>(dp + 8) = o1;
}

// ---------- LayerNorm (torch: unbiased std, /(std+eps)) ----------
__global__ __launch_bounds__(256) void ln_k(const float* __restrict__ x,
                                            const float* __restrict__ alpha,
                                            const float* __restrict__ bias,
                                            unsigned short* __restrict__ out) {
  int row = blockIdx.x, t = threadIdx.x;
  float4 v = reinterpret_cast<const float4*>(x + (size_t)row * D_)[t];
  float s = v.x + v.y + v.z + v.w;
  float q = v.x * v.x + v.y * v.y + v.z * v.z + v.w * v.w;
#pragma unroll
  for (int off = 32; off > 0; off >>= 1) {
    s += __shfl_down(s, off);
    q += __shfl_down(q, off);
  }
  __shared__ float ss[4], sq[4], stat[2];
  if ((t & 63) == 0) { ss[t >> 6] = s; sq[t >> 6] = q; }
  __syncthreads();
  if (t == 0) {
    float S = ss[0] + ss[1] + ss[2] + ss[3];
    float Q = sq[0] + sq[1] + sq[2] + sq[3];
    float mean = S * (1.0f / D_);
    float var = fmaxf((Q - D_ * mean * mean) * (1.0f / (D_ - 1)), 0.0f);
    stat[0] = mean;
    stat[1] = 1.0f / (sqrtf(var) + 1e-6f);
  }
  __syncthreads();
  float mean = stat[0], inv = stat[1];
  float4 a = reinterpret_cast<const float4*>(alpha)[t];
  float4 b = reinterpret_cast<const float4*>(bias)[t];
  ushort4 o;
  o.x = f2bf((v.x - mean) * inv * a.x + b.x);
  o.y = f2bf((v.y - mean) * inv * a.y + b.y);
  o.z = f2bf((v.z - mean) * inv * a.z + b.z);
  o.w = f2bf((v.w - mean) * inv * a.w + b.w);
  reinterpret_cast<ushort4*>(out + (size_t)row * D_)[t] = o;
}

// ---------- GEMM core: 128x128 tile, BK=64 (two 32-k panels / barrier) ----
// As/Bs: 128*64 shorts each; panel p at offset p*4096 shorts.
__device__ __forceinline__ void gemm_core(const unsigned short* __restrict__ A,
                                          const unsigned short* __restrict__ Wt,
                                          int m0, int n0, int K,
                                          unsigned short* As, unsigned short* Bs,
                                          f32x4 (&acc)[4][4]) {
  const int t = threadIdx.x;
  const int wv = t >> 6, lane = t & 63, quad = lane >> 4, l16 = lane & 15;
  const int wm = wv >> 1, wn = wv & 1;
  const int row0 = wv * 32 + (lane >> 2);
  const int row1 = row0 + 16;
  const int slot = lane & 3;
  const int kof0 = ((slot ^ ((row0 >> 1) & 3)) << 3);
  const int kof1 = ((slot ^ ((row1 >> 1) & 3)) << 3);
  const unsigned short* Ag0 = A + (size_t)(m0 + row0) * K + kof0;
  const unsigned short* Ag1 = A + (size_t)(m0 + row1) * K + kof1;
  const unsigned short* Bg0 = Wt + (size_t)(n0 + row0) * K + kof0;
  const unsigned short* Bg1 = Wt + (size_t)(n0 + row1) * K + kof1;
  unsigned short* la0 = &As[(wv * 32) * 32];
  unsigned short* la1 = &As[(wv * 32 + 16) * 32];
  unsigned short* lb0 = &Bs[(wv * 32) * 32];
  unsigned short* lb1 = &Bs[(wv * 32 + 16) * 32];

  for (int k0 = 0; k0 < K; k0 += 64) {
    gload16(Ag0, la0);
    gload16(Ag0 + 32, la0 + 4096);
    gload16(Ag1, la1);
    gload16(Ag1 + 32, la1 + 4096);
    gload16(Bg0, lb0);
    gload16(Bg0 + 32, lb0 + 4096);
    gload16(Bg1, lb1);
    gload16(Bg1 + 32, lb1 + 4096);
    __syncthreads();
#pragma unroll
    for (int p = 0; p < 2; ++p) {
      short8 af[4], bf[4];
#pragma unroll
      for (int mt = 0; mt < 4; ++mt) {
        int r = wm * 64 + mt * 16 + l16;
        af[mt] = *reinterpret_cast<const short8*>(
            &As[p * 4096 + r * 32 + ((quad ^ ((r >> 1) & 3)) << 3)]);
      }
#pragma unroll
      for (int nt = 0; nt < 4; ++nt) {
        int r = wn * 64 + nt * 16 + l16;
        bf[nt] = *reinterpret_cast<const short8*>(
            &Bs[p * 4096 + r * 32 + ((quad ^ ((r >> 1) & 3)) << 3)]);
      }
#pragma unroll
      for (int mt = 0; mt < 4; ++mt)
#pragma unroll
        for (int nt = 0; nt < 4; ++nt)
          acc[mt][nt] = __builtin_amdgcn_mfma_f32_16x16x32_bf16(
              af[mt], bf[nt], acc[mt][nt], 0, 0, 0);
    }
    __syncthreads();
    Ag0 += 64; Ag1 += 64; Bg0 += 64; Bg1 += 64;
  }
}

// ---------- generic GEMM: flags 1=bf16 out, 2=gelu; res: fp32 residual ----
__global__ __launch_bounds__(256) void gemm_k(
    const unsigned short* __restrict__ A, const unsigned short* __restrict__ Wt,
    const float* __restrict__ bias, const float* __restrict__ res,
    void* __restrict__ outp, int M, int N, int K, int flags) {
  __shared__ unsigned short As[128 * 64];
  __shared__ unsigned short Bs[128 * 64];
  const int t = threadIdx.x;
  const int m0 = blockIdx.y * 128, n0 = blockIdx.x * 128;
  const int wv = t >> 6, lane = t & 63, quad = lane >> 4, l16 = lane & 15;
  const int wm = wv >> 1, wn = wv & 1;
  f32x4 acc[4][4] = {};
  gemm_core(A, Wt, m0, n0, K, As, Bs, acc);

  const bool obf = flags & 1, dog = flags & 2;
#pragma unroll
  for (int nt = 0; nt < 4; ++nt) {
    int col = n0 + wn * 64 + nt * 16 + l16;
    float bv = bias[col];
#pragma unroll
    for (int mt = 0; mt < 4; ++mt) {
#pragma unroll
      for (int r = 0; r < 4; ++r) {
        int row = m0 + wm * 64 + mt * 16 + quad * 4 + r;
        float v = acc[mt][nt][r] + bv;
        if (res) v += res[(size_t)row * N + col];
        if (dog) {
          float e = __expf(1.5957691216057308f * (v + 0.044715f * v * v * v));
          float th = 1.0f - 2.0f / (1.0f + e);
          v = 0.5f * v * (1.0f + th);
        }
        if (obf)
          ((unsigned short*)outp)[(size_t)row * N + col] = f2bf(v);
        else
          ((float*)outp)[(size_t)row * N + col] = v;
      }
    }
  }
}

// ---------- fused QKV GEMM: N=3072; seg0->Q nat, seg1->K nat, seg2->VT ----
__global__ __launch_bounds__(256) void gemmqkv_k(
    const unsigned short* __restrict__ A, const unsigned short* __restrict__ Wt,
    const float* __restrict__ bq, const float* __restrict__ bk,
    const float* __restrict__ bv, unsigned short* __restrict__ outq,
    unsigned short* __restrict__ outk, unsigned short* __restrict__ outvt,
    int M, int K) {
  __shared__ unsigned short As[128 * 64];
  __shared__ unsigned short Bs[128 * 64];
  const int t = threadIdx.x;
  const int m0 = blockIdx.y * 128, n0 = blockIdx.x * 128;
  const int wv = t >> 6, lane = t & 63, quad = lane >> 4, l16 = lane & 15;
  const int wm = wv >> 1, wn = wv & 1;
  f32x4 acc[4][4] = {};
  gemm_core(A, Wt, m0, n0, K, As, Bs, acc);

  const int seg = n0 >> 10;
  const int nb = n0 & 1023;
  const float* bias = (seg == 0) ? bq : (seg == 1) ? bk : bv;
  if (seg < 2) {
    unsigned short* o = (seg == 0) ? outq : outk;
#pragma unroll
    for (int nt = 0; nt < 4; ++nt) {
      int col = nb + wn * 64 + nt * 16 + l16;
      float bvv = bias[col];
#pragma unroll
      for (int mt = 0; mt < 4; ++mt)
#pragma unroll
        for (int r = 0; r < 4; ++r) {
          int row = m0 + wm * 64 + mt * 16 + quad * 4 + r;
          o[(size_t)row * D_ + col] = f2bf(acc[mt][nt][r] + bvv);
        }
    }
  } else {  // V -> VT[b][h][dk][S]
#pragma unroll
    for (int nt = 0; nt < 4; ++nt) {
      int col = nb + wn * 64 + nt * 16 + l16;
      float bvv = bias[col];
      int h = col >> 6, dk = col & 63;
#pragma unroll
      for (int mt = 0; mt < 4; ++mt) {
        int m = m0 + wm * 64 + mt * 16 + quad * 4;
        int b = m >> 11, sidx = m & 2047;
        ushort4 o;
        o.x = f2bf(acc[mt][nt][0] + bvv);
        o.y = f2bf(acc[mt][nt][1] + bvv);
        o.z = f2bf(acc[mt][nt][2] + bvv);
        o.w = f2bf(acc[mt][nt][3] + bvv);
        *reinterpret_cast<ushort4*>(
            &outvt[(((size_t)(b * 16 + h) * 64 + dk) * 2048 + sidx)]) = o;
      }
    }
  }
}

// ---------- paired-tile causal flash attention ----------
// 512 blocks: (b,h) x pair p; q-tiles {p, 15-p} -> uniform 34 key-tiles/block.
__device__ __forceinline__ void sm_update(f32x4 (&sc)[2][4], int qbase, int k0,
                                          float (&m_r)[2][4],
                                          float (&l_r)[2][4], f32x4 (&O)[2][4],
                                          unsigned short* PsBase, int quad,
                                          int l16) {
  const bool full = (k0 + 63) <= qbase;
#pragma unroll
  for (int mt = 0; mt < 2; ++mt)
#pragma unroll
    for (int r = 0; r < 4; ++r) {
      int row = qbase + mt * 16 + quad * 4 + r;
      float s[4];
#pragma unroll
      for (int nh = 0; nh < 4; ++nh) {
        s[nh] = sc[mt][nh][r] * 0.125f;
        if (!full && (k0 + nh * 16 + l16) > row) s[nh] = -1e9f;
      }
      float mx = fmaxf(fmaxf(s[0], s[1]), fmaxf(s[2], s[3]));
#pragma unroll
      for (int off = 1; off < 16; off <<= 1) mx = fmaxf(mx, __shfl_xor(mx, off));
      float mn = fmaxf(m_r[mt][r], mx);
      float p[4], rs = 0.0f;
#pragma unroll
      for (int nh = 0; nh < 4; ++nh) { p[nh] = __expf(s[nh] - mn); rs += p[nh]; }
#pragma unroll
      for (int off = 1; off < 16; off <<= 1) rs += __shfl_xor(rs, off);
      float al = __expf(m_r[mt][r] - mn);
      m_r[mt][r] = mn;
      l_r[mt][r] = l_r[mt][r] * al + rs;
      unsigned short* pr = PsBase + (mt * 16 + quad * 4 + r) * 72 + l16;
#pragma unroll
      for (int nh = 0; nh < 4; ++nh) pr[nh * 16] = f2bf(p[nh]);
#pragma unroll
      for (int nd = 0; nd < 4; ++nd) O[mt][nd][r] *= al;
    }
}

__global__ __launch_bounds__(256, 2) void attn_k(
    const unsigned short* __restrict__ Q, const unsigned short* __restrict__ Kg,
    const unsigned short* __restrict__ VT, unsigned short* __restrict__ Og) {
  __shared__ unsigned short Ks[64 * 64];      // [k][d], XOR seg-swizzled
  __shared__ unsigned short Vs[64 * 64];      // [d][k], XOR seg-swizzled
  __shared__ unsigned short Ps[4 * 64 * 72];  // per-wave 64 rows (hi 32, lo 32)
  const int t = threadIdx.x;
  const int bid = blockIdx.x;
  const int pair = bid >> 6, bh = bid & 63;
  const int b = bh >> 4, h = bh & 15;
  const int lo = pair, hi = 15 - pair;
  const int w = t >> 6, lane = t & 63, quad = lane >> 4, l16 = lane & 15;
  const int qhi0 = hi * 128 + w * 32, qlo0 = lo * 128 + w * 32;

  short8 qfh[2][2], qfl[2][2];
#pragma unroll
  for (int mt = 0; mt < 2; ++mt)
#pragma unroll
    for (int dc = 0; dc < 2; ++dc) {
      qfh[mt][dc] = *reinterpret_cast<const short8*>(
          Q + (size_t)(b * S_ + qhi0 + mt * 16 + l16) * D_ + h * 64 + dc * 32 +
          quad * 8);
      qfl[mt][dc] = *reinterpret_cast<const short8*>(
          Q + (size_t)(b * S_ + qlo0 + mt * 16 + l16) * D_ + h * 64 + dc * 32 +
          quad * 8);
    }

  f32x4 Oh[2][4] = {}, Ol[2][4] = {};
  float mh[2][4], lh[2][4], ml[2][4], ll[2][4];
#pragma unroll
  for (int mt = 0; mt < 2; ++mt)
#pragma unroll
    for (int r = 0; r < 4; ++r) {
      mh[mt][r] = -1e30f; lh[mt][r] = 0.0f;
      ml[mt][r] = -1e30f; ll[mt][r] = 0.0f;
    }

  const int ktiles = 2 * hi + 2, lotiles = 2 * lo + 2;
  // staging (gload16): wave w covers 16 rows [w*16, w*16+16); lane -> row
  // w*16 + (lane>>3), phys seg lane&7 holds logical seg (lane&7)^(row&7).
  const int srow = w * 16 + (lane >> 3);
  const int sseg = ((lane & 7) ^ (srow & 7)) * 8;
  const int srow2 = srow + 8;
  const int sseg2 = ((lane & 7) ^ (srow2 & 7)) * 8;
  const unsigned short* Kp0 = Kg + (size_t)(b * S_ + srow) * D_ + h * 64 + sseg;
  const unsigned short* Kp1 =
      Kg + (size_t)(b * S_ + srow2) * D_ + h * 64 + sseg2;
  const unsigned short* Vp0 =
      VT + ((size_t)(b * 16 + h) * 64 + srow) * 2048 + sseg;
  const unsigned short* Vp1 =
      VT + ((size_t)(b * 16 + h) * 64 + srow2) * 2048 + sseg2;
  unsigned short* lk0 = &Ks[(w * 16) * 64];
  unsigned short* lk1 = &Ks[(w * 16 + 8) * 64];
  unsigned short* lv0 = &Vs[(w * 16) * 64];
  unsigned short* lv1 = &Vs[(w * 16 + 8) * 64];
  unsigned short* PsW = &Ps[w * 64 * 72];

  for (int kt = 0; kt < ktiles; ++kt) {
    gload16(Kp0, lk0);
    gload16(Kp1, lk1);
    gload16(Vp0, lv0);
    gload16(Vp1, lv1);
    __syncthreads();

    short8 kf[4][2];
#pragma unroll
    for (int nh = 0; nh < 4; ++nh)
#pragma unroll
      for (int kc = 0; kc < 2; ++kc) {
        int r = nh * 16 + l16;
        int lseg = kc * 4 + quad;  // logical 16B seg
        kf[nh][kc] = *reinterpret_cast<const short8*>(
            &Ks[r * 64 + ((lseg ^ (r & 7)) << 3)]);
      }

    const bool dolo = kt < lotiles;

    f32x4 sc[2][4] = {};
#pragma unroll
    for (int nh = 0; nh < 4; ++nh)
#pragma unroll
      for (int mt = 0; mt < 2; ++mt) {
        sc[mt][nh] = __builtin_amdgcn_mfma_f32_16x16x32_bf16(
            qfh[mt][0], kf[nh][0], sc[mt][nh], 0, 0, 0);
        sc[mt][nh] = __builtin_amdgcn_mfma_f32_16x16x32_bf16(
            qfh[mt][1], kf[nh][1], sc[mt][nh], 0, 0, 0);
      }
    sm_update(sc, qhi0, kt * 64, mh, lh, Oh, PsW, quad, l16);

    if (dolo) {
      f32x4 sl[2][4] = {};
#pragma unroll
      for (int nh = 0; nh < 4; ++nh)
#pragma unroll
        for (int mt = 0; mt < 2; ++mt) {
          sl[mt][nh] = __builtin_amdgcn_mfma_f32_16x16x32_bf16(
              qfl[mt][0], kf[nh][0], sl[mt][nh], 0, 0, 0);
          sl[mt][nh] = __builtin_amdgcn_mfma_f32_16x16x32_bf16(
              qfl[mt][1], kf[nh][1], sl[mt][nh], 0, 0, 0);
        }
      sm_update(sl, qlo0, kt * 64, ml, ll, Ol, PsW + 32 * 72, quad, l16);
    }

    __builtin_amdgcn_sched_barrier(0);

    short8 vf[4][2];
#pragma unroll
    for (int nd = 0; nd < 4; ++nd)
#pragma unroll
      for (int kc = 0; kc < 2; ++kc) {
        int r = nd * 16 + l16;
        int lseg = kc * 4 + quad;
        vf[nd][kc] = *reinterpret_cast<const short8*>(
            &Vs[r * 64 + ((lseg ^ (r & 7)) << 3)]);
      }
    short8 pf[2][2];
#pragma unroll
    for (int mt = 0; mt < 2; ++mt)
#pragma unroll
      for (int kc = 0; kc < 2; ++kc)
        pf[mt][kc] = *reinterpret_cast<const short8*>(
            &PsW[(mt * 16 + l16) * 72 + kc * 32 + quad * 8]);
#pragma unroll
    for (int mt = 0; mt < 2; ++mt)
#pragma unroll
      for (int nd = 0; nd < 4; ++nd) {
        Oh[mt][nd] = __builtin_amdgcn_mfma_f32_16x16x32_bf16(
            pf[mt][0], vf[nd][0], Oh[mt][nd], 0, 0, 0);
        Oh[mt][nd] = __builtin_amdgcn_mfma_f32_16x16x32_bf16(
            pf[mt][1], vf[nd][1], Oh[mt][nd], 0, 0, 0);
      }
    if (dolo) {
      short8 pl[2][2];
#pragma unroll
      for (int mt = 0; mt < 2; ++mt)
#pragma unroll
        for (int kc = 0; kc < 2; ++kc)
          pl[mt][kc] = *reinterpret_cast<const short8*>(
              &PsW[(32 + mt * 16 + l16) * 72 + kc * 32 + quad * 8]);
#pragma unroll
      for (int mt = 0; mt < 2; ++mt)
#pragma unroll
        for (int nd = 0; nd < 4; ++nd) {
          Ol[mt][nd] = __builtin_amdgcn_mfma_f32_16x16x32_bf16(
              pl[mt][0], vf[nd][0], Ol[mt][nd], 0, 0, 0);
          Ol[mt][nd] = __builtin_amdgcn_mfma_f32_16x16x32_bf16(
              pl[mt][1], vf[nd][1], Ol[mt][nd], 0, 0, 0);
        }
    }
    __syncthreads();
    Kp0 += (size_t)64 * D_;
    Kp1 += (size_t)64 * D_;
    Vp0 += 64;
    Vp1 += 64;
  }

#pragma unroll
  for (int mt = 0; mt < 2; ++mt)
#pragma unroll
    for (int nd = 0; nd < 4; ++nd)
#pragma unroll
      for (int r = 0; r < 4; ++r) {
        int rh = qhi0 + mt * 16 + quad * 4 + r;
        Og[(size_t)(b * S_ + rh) * D_ + h * 64 + nd * 16 + l16] =
            f2bf(Oh[mt][nd][r] / lh[mt][r]);
        int rl = qlo0 + mt * 16 + quad * 4 + r;
        Og[(size_t)(b * S_ + rl) * D_ + h * 64 + nd * 16 + l16] =
            f2bf(Ol[mt][nd][r] / ll[mt][r]);
      }
}

extern "C" void kernel_launch(void* const* d_in, const int* in_sizes, int n_in,
                              void* d_out, int out_size, void* d_ws,
                              size_t ws_size, hipStream_t stream) {
  const float* x = (const float*)d_in[0];
  const float* Wq = (const float*)d_in[2];
  const float* bq = (const float*)d_in[3];
  const float* Wk = (const float*)d_in[4];
  const float* bk = (const float*)d_in[5];
  const float* Wv = (const float*)d_in[6];
  const float* bv = (const float*)d_in[7];
  const float* Wo = (const float*)d_in[8];
  const float* bo = (const float*)d_in[9];
  const float* W1 = (const float*)d_in[10];
  const float* b1 = (const float*)d_in[11];
  const float* W2 = (const float*)d_in[12];
  const float* b2 = (const float*)d_in[13];
  const float* alpha1 = (const float*)d_in[14];
  const float* bias1 = (const float*)d_in[15];
  const float* alpha2 = (const float*)d_in[16];
  const float* bias2 = (const float*)d_in[17];
  float* out = (float*)d_out;

  char* ws = (char*)d_ws;
  const size_t MB = 1024 * 1024;
  unsigned short* wqT = (unsigned short*)(ws + 0 * MB);  // fused [3072][1024]
  unsigned short* wkT = (unsigned short*)(ws + 2 * MB);
  unsigned short* wvT = (unsigned short*)(ws + 4 * MB);
  unsigned short* woT = (unsigned short*)(ws + 6 * MB);
  unsigned short* w1T = (unsigned short*)(ws + 8 * MB);
  unsigned short* w2T = (unsigned short*)(ws + 10 * MB);
  unsigned short* x2a = (unsigned short*)(ws + 12 * MB);  // norm1 / attn out
  unsigned short* qb = (unsigned short*)(ws + 28 * MB);   // Q / norm2
  unsigned short* kb = (unsigned short*)(ws + 44 * MB);   // K / FF hidden
  unsigned short* vtb = (unsigned short*)(ws + 60 * MB);  // VT[b][h][d][s]

  dim3 tg(16, 16);
  tcast_k<<<tg, dim3(256), 0, stream>>>(Wq, wqT, D_, D_);
  tcast_k<<<tg, dim3(256), 0, stream>>>(Wk, wkT, D_, D_);
  tcast_k<<<tg, dim3(256), 0, stream>>>(Wv, wvT, D_, D_);
  tcast_k<<<tg, dim3(256), 0, stream>>>(Wo, woT, D_, D_);
  tcast_k<<<tg, dim3(256), 0, stream>>>(W1, w1T, DFF_, D_);
  tcast_k<<<tg, dim3(256), 0, stream>>>(W2, w2T, D_, DFF_);

  const int M = B_ * S_;  // 8192
  ln_k<<<dim3(M), dim3(256), 0, stream>>>(x, alpha1, bias1, x2a);

  gemmqkv_k<<<dim3(24, 64), dim3(256), 0, stream>>>(x2a, wqT, bq, bk, bv, qb,
                                                    kb, vtb, M, D_);

  attn_k<<<dim3(512), dim3(256), 0, stream>>>(qb, kb, vtb, x2a);

  dim3 gg(D_ / 128, M / 128);  // (8, 64)
  gemm_k<<<gg, dim3(256), 0, stream>>>(x2a, woT, bo, x, out, M, D_, D_, 0);

  ln_k<<<dim3(M), dim3(256), 0, stream>>>(out, alpha2, bias2, qb);

  gemm_k<<<gg, dim3(256), 0, stream>>>(qb, w1T, b1, nullptr, kb, M, DFF_, D_, 3);

  gemm_k<<<gg, dim3(256), 0, stream>>>(kb, w2T, b2, out, out, M, D_, DFF_, 0);
}